// Round 4
// baseline (239.399 us; speedup 1.0000x reference)
//
#include <hip/hip_runtime.h>

#define Bv 256
#define Tv 200
#define Cv 40
#define H1v 512
#define H2v 256
#define Ov 12
#define THv 1.0f

typedef unsigned long long u64;
typedef unsigned int u32;
typedef float f32x4 __attribute__((ext_vector_type(4)));

// ---------------------------------------------------------------------------
// One block per batch element (256 blocks = 256 CUs), 512 threads (8 waves).
//   tid < 512 : owns layer-1 hidden unit `tid`
//   tid < 256 : also owns layer-2 hidden unit `tid`
//   tid < 12  : also owns output unit `tid`
//
// Round-4 fix: __launch_bounds__(512, 2). Grid = 1 block/CU (2 waves/SIMD),
// so the allocator gets a 256-VGPR budget and the per-thread W1 row (40
// VGPRs) actually stays RESIDENT. Rounds 1-3 compiled at 40-48 VGPRs and
// re-fetched all of W1 from L2 every timestep (80 KB/CU/step = 46 B/cyc/CU,
// i.e. at the per-CU L2 ceiling) — that was the real bottleneck.
//
// x_t (block-uniform, 160 B) comes in on the scalar pipe via
// s_load_dwordx4, software-prefetched one step ahead; the block's x slice
// is L2-warmed once at startup. Per-step vector-pipe memory traffic is one
// broadcast ds_read_b64 (spike flags).
//
// Spike exchange: per-wave ballot words + packed {any1,any2} flags,
// triple-buffered (read (t-1)%3, write t%3, zero (t+1)%3), ONE barrier per
// step. Software pipeline: iteration t = L1(t), L2(t-1), Out(t-2); 2 drain
// iterations. Cold (spiking) paths do mask-driven gathers — never taken on
// this data (absmax == 0) but keep the kernel correct in general.
// ---------------------------------------------------------------------------
__global__ __launch_bounds__(512, 2) void snn_main(
    const float* __restrict__ x,
    const float* __restrict__ W1,
    const float* __restrict__ Wrec,
    const float* __restrict__ W2,
    const float* __restrict__ Wout,
    const float* __restrict__ alpha1, const float* __restrict__ rho1, const float* __restrict__ ba1,
    const float* __restrict__ alpha2, const float* __restrict__ rho2, const float* __restrict__ ba2,
    const float* __restrict__ beta_out,
    float* __restrict__ out)
{
    __shared__ __align__(8) u32 s_flags[3][2];   // [slot][{any1, any2}]
    __shared__ u64 s_m1[3][8];                   // spk1 ballot words
    __shared__ u64 s_m2[3][4];                   // spk2 ballot words

    const int b    = blockIdx.x;
    const int tid  = threadIdx.x;
    const int lane = tid & 63;
    const int wv   = tid >> 6;

    // --- per-thread W1 row in registers (40 floats = 40 VGPRs, resident) ---
    f32x4 w1r[10];
    {
        const f32x4* p = (const f32x4*)(W1 + tid * Cv);
        #pragma unroll
        for (int i = 0; i < 10; ++i) w1r[i] = p[i];
    }
    const float al1 = alpha1[tid], rh1 = rho1[tid], bb1 = ba1[tid];
    float v1 = 0.f, a1 = 0.f, spk1 = 0.f;
    float al2 = 0.f, rh2 = 0.f, bb2 = 0.f, v2 = 0.f, a2 = 0.f;
    if (tid < H2v) { al2 = alpha2[tid]; rh2 = rho2[tid]; bb2 = ba2[tid]; }
    const float beta = beta_out[0];
    float vout = 0.f, osum = 0.f;

    const float* xb = x + (size_t)b * (Tv * Cv);

    // --- warm this block's x slice (32 KB) into L2 so per-step s_loads hit ---
    {
        float dummy = 0.f;
        for (int i = tid; i < Tv * Cv; i += 512) dummy += xb[i];
        asm volatile("" :: "v"(dummy));
    }

    if (tid < 3) { s_flags[tid][0] = 0u; s_flags[tid][1] = 0u; }

    // --- prefetch x row 0 into SGPRs (scalar pipe) ---
    f32x4 q0 = {0.f,0.f,0.f,0.f}, q1 = q0, q2 = q0, q3 = q0, q4 = q0,
          q5 = q0, q6 = q0, q7 = q0, q8 = q0, q9 = q0;
    {
        const float* xr = xb;
        asm volatile(
            "s_load_dwordx4 %0, %10, 0x0\n\t"
            "s_load_dwordx4 %1, %10, 0x10\n\t"
            "s_load_dwordx4 %2, %10, 0x20\n\t"
            "s_load_dwordx4 %3, %10, 0x30\n\t"
            "s_load_dwordx4 %4, %10, 0x40\n\t"
            "s_load_dwordx4 %5, %10, 0x50\n\t"
            "s_load_dwordx4 %6, %10, 0x60\n\t"
            "s_load_dwordx4 %7, %10, 0x70\n\t"
            "s_load_dwordx4 %8, %10, 0x80\n\t"
            "s_load_dwordx4 %9, %10, 0x90"
            : "+s"(q0), "+s"(q1), "+s"(q2), "+s"(q3), "+s"(q4),
              "+s"(q5), "+s"(q6), "+s"(q7), "+s"(q8), "+s"(q9)
            : "s"(xr));
    }

    __syncthreads();

    int rs = 2, wsl = 0, zsl = 1;   // read / write / zero slots (rotate)
    for (int t = 0; t < Tv + 2; ++t) {
        // ---- prev-step spike flags: one broadcast ds_read_b64 ----
        const u64 fl  = *(const u64*)(&s_flags[rs][0]);
        const u32 any1 = (u32)fl;
        const u32 any2 = (u32)(fl >> 32);

        // ================= L1 update for step t =================
        if (t < Tv) {
            // wait for the prefetched x row (tied operands = ordering fence)
            asm volatile("s_waitcnt lgkmcnt(0)"
                : "+s"(q0), "+s"(q1), "+s"(q2), "+s"(q3), "+s"(q4),
                  "+s"(q5), "+s"(q6), "+s"(q7), "+s"(q8), "+s"(q9));

            float c0 = 0.f, c1 = 0.f, c2 = 0.f, c3 = 0.f;
#define DOT_Q(Q, I) \
            c0 += (Q).x * w1r[I].x; c1 += (Q).y * w1r[I].y; \
            c2 += (Q).z * w1r[I].z; c3 += (Q).w * w1r[I].w;
            DOT_Q(q0, 0) DOT_Q(q1, 1) DOT_Q(q2, 2) DOT_Q(q3, 3) DOT_Q(q4, 4)
            DOT_Q(q5, 5) DOT_Q(q6, 6) DOT_Q(q7, 7) DOT_Q(q8, 8) DOT_Q(q9, 9)
#undef DOT_Q
            float acc = (c0 + c1) + (c2 + c3);

            // prefetch next row (redefines the q SGPRs; data flow orders
            // this after the consumption above)
            if (t + 1 < Tv) {
                const float* xr = xb + (t + 1) * Cv;
                asm volatile(
                    "s_load_dwordx4 %0, %10, 0x0\n\t"
                    "s_load_dwordx4 %1, %10, 0x10\n\t"
                    "s_load_dwordx4 %2, %10, 0x20\n\t"
                    "s_load_dwordx4 %3, %10, 0x30\n\t"
                    "s_load_dwordx4 %4, %10, 0x40\n\t"
                    "s_load_dwordx4 %5, %10, 0x50\n\t"
                    "s_load_dwordx4 %6, %10, 0x60\n\t"
                    "s_load_dwordx4 %7, %10, 0x70\n\t"
                    "s_load_dwordx4 %8, %10, 0x80\n\t"
                    "s_load_dwordx4 %9, %10, 0x90"
                    : "+s"(q0), "+s"(q1), "+s"(q2), "+s"(q3), "+s"(q4),
                      "+s"(q5), "+s"(q6), "+s"(q7), "+s"(q8), "+s"(q9)
                    : "s"(xr));
            }

            if (any1) {   // recurrent gather — cold path, never on this data
                #pragma unroll
                for (int w = 0; w < 8; ++w) {
                    u64 m = s_m1[rs][w];
                    while (m) {
                        const int j = (w << 6) + __builtin_ctzll(m);
                        m &= (m - 1);
                        acc += Wrec[tid * H1v + j];
                    }
                }
            }
            v1 = al1 * (v1 - spk1 * THv) + (1.f - al1) * (acc - a1);
            const bool sp = (v1 >= THv);
            spk1 = sp ? 1.f : 0.f;
            a1 = rh1 * a1 + bb1 * spk1;
            const u64 bal = __ballot(sp);
            if (lane == 0) {
                s_m1[wsl][wv] = bal;
                if (bal) s_flags[wsl][0] = 1u;
            }
        }

        // ================= L2 update for step t-1 =================
        if ((tid < H2v) & (t >= 1) & (t <= Tv)) {
            float acc2 = 0.f;
            if (any1) {   // cold path
                #pragma unroll
                for (int w = 0; w < 8; ++w) {
                    u64 m = s_m1[rs][w];
                    while (m) {
                        const int j = (w << 6) + __builtin_ctzll(m);
                        m &= (m - 1);
                        acc2 += W2[tid * H1v + j];
                    }
                }
            }
            v2 = al2 * v2 + (1.f - al2) * (acc2 - a2);
            const bool sp2 = (v2 >= THv);
            a2 = rh2 * a2 + bb2 * (sp2 ? 1.f : 0.f);
            const u64 bal2 = __ballot(sp2);
            if (lane == 0) {
                s_m2[wsl][wv] = bal2;
                if (bal2) s_flags[wsl][1] = 1u;
            }
        }

        // ================= Out update for step t-2 =================
        if ((tid < Ov) & (t >= 2)) {
            float io = 0.f;
            if (any2) {   // cold path
                #pragma unroll
                for (int w = 0; w < 4; ++w) {
                    u64 m = s_m2[rs][w];
                    while (m) {
                        const int j = (w << 6) + __builtin_ctzll(m);
                        m &= (m - 1);
                        io += Wout[tid * H2v + j];
                    }
                }
            }
            vout = beta * vout + (1.f - beta) * io;
            osum += vout;
        }

        // zero the slot that becomes the write slot next iteration
        if (tid == 257) *(u64*)(&s_flags[zsl][0]) = 0ull;

        __syncthreads();
        const int tmp = rs; rs = wsl; wsl = zsl; zsl = tmp;
    }

    if (tid < Ov) out[b * Ov + tid] = osum / (float)Tv;
}

extern "C" void kernel_launch(void* const* d_in, const int* in_sizes, int n_in,
                              void* d_out, int out_size, void* d_ws, size_t ws_size,
                              hipStream_t stream)
{
    const float* x       = (const float*)d_in[0];
    const float* W1      = (const float*)d_in[1];
    const float* Wrec    = (const float*)d_in[2];
    const float* W2      = (const float*)d_in[3];
    const float* Wout    = (const float*)d_in[4];
    const float* alpha1  = (const float*)d_in[5];
    const float* rho1    = (const float*)d_in[6];
    const float* ba1     = (const float*)d_in[7];
    const float* alpha2  = (const float*)d_in[8];
    const float* rho2    = (const float*)d_in[9];
    const float* ba2     = (const float*)d_in[10];
    const float* beta_o  = (const float*)d_in[11];
    float* out = (float*)d_out;

    snn_main<<<dim3(Bv), dim3(512), 0, stream>>>(
        x, W1, Wrec, W2, Wout,
        alpha1, rho1, ba1, alpha2, rho2, ba2, beta_o, out);
}

// Round 6
// 235.960 us; speedup vs baseline: 1.0146x; 1.0146x over previous
//
#include <hip/hip_runtime.h>

#define Bv 256
#define Tv 200
#define Cv 40
#define H1v 512
#define H2v 256
#define Ov 12
#define THv 1.0f

typedef unsigned long long u64;
typedef unsigned int u32;
typedef float f32x4 __attribute__((ext_vector_type(4)));

// ---------------------------------------------------------------------------
// One block per batch element (256 blocks = 256 CUs), 512 threads (8 waves).
//   tid < 512 : owns layer-1 hidden unit `tid`
//   tid < 256 : also owns layer-2 hidden unit `tid`
//   tid < 12  : also owns output unit `tid`
//
// Root cause of rounds 1-4 (~2000 cyc/step): the per-thread W1-row loads are
// invariant -> rematerializable, so the allocator RE-EXECUTED them every
// iteration instead of keeping 40 VGPRs live across the barrier loop
// (VGPR_Count was 40 in every round). That is an 80 KB/CU/step L2 re-fetch
// = ~1430 cyc/step at the per-CU L2 ceiling. R5 tried asm loads but missed
// early-clobber on async global_load outputs -> address clobber -> fault.
//
// R6 fix: normal C++ loads + empty `asm volatile("" : "+v"(x))` PIN. The
// pinned value is defined by a once-executed volatile asm -> cannot be
// rematerialized; with __launch_bounds__(512,2) (256-VGPR budget) it stays
// resident. x-row s_load prefetch asm is overlap-safe: the address is an
// OUTPUT operand, so it gets registers distinct from all data outputs.
//
// x_t (block-uniform, 160 B) comes in on the scalar pipe via s_load_dwordx4,
// prefetched one step ahead; the block's x slice is L2-warmed once.
// Spike exchange: per-wave ballot words + packed {any1,any2} flags,
// triple-buffered (read (t-1)%3, write t%3, zero (t+1)%3), ONE barrier per
// step. Pipeline: iteration t = L1(t), L2(t-1), Out(t-2); 2 drain iters.
// Cold (spiking) gather paths never fire on this data (absmax == 0) but
// keep the kernel correct in general.
// ---------------------------------------------------------------------------
__global__ __launch_bounds__(512, 2) void snn_main(
    const float* __restrict__ x,
    const float* __restrict__ W1,
    const float* __restrict__ Wrec,
    const float* __restrict__ W2,
    const float* __restrict__ Wout,
    const float* __restrict__ alpha1, const float* __restrict__ rho1, const float* __restrict__ ba1,
    const float* __restrict__ alpha2, const float* __restrict__ rho2, const float* __restrict__ ba2,
    const float* __restrict__ beta_out,
    float* __restrict__ out)
{
    __shared__ __align__(8) u32 s_flags[3][2];   // [slot][{any1, any2}]
    __shared__ u64 s_m1[3][8];                   // spk1 ballot words
    __shared__ u64 s_m2[3][4];                   // spk2 ballot words

    const int b    = blockIdx.x;
    const int tid  = threadIdx.x;
    const int lane = tid & 63;
    const int wv   = tid >> 6;

    // --- per-thread W1 row: load, then PIN (un-rematerializable) ---
    f32x4 w1r[10];
    {
        const f32x4* p = (const f32x4*)(W1 + tid * Cv);
        #pragma unroll
        for (int i = 0; i < 10; ++i) w1r[i] = p[i];
        #pragma unroll
        for (int i = 0; i < 10; ++i) asm volatile("" : "+v"(w1r[i]));
    }

    // --- per-thread neuron constants: load + pin ---
    const int t2 = tid & (H2v - 1);
    float al1 = alpha1[tid], rh1 = rho1[tid], bb1 = ba1[tid];
    float al2 = alpha2[t2],  rh2 = rho2[t2],  bb2 = ba2[t2];
    asm volatile("" : "+v"(al1), "+v"(rh1), "+v"(bb1),
                      "+v"(al2), "+v"(rh2), "+v"(bb2));

    float v1 = 0.f, a1 = 0.f, spk1 = 0.f;
    float v2 = 0.f, a2 = 0.f;
    float beta = beta_out[0];
    asm volatile("" : "+s"(beta));
    float vout = 0.f, osum = 0.f;

    const float* xb = x + (size_t)b * (Tv * Cv);

    // --- warm this block's x slice (32 KB) into L2 so per-step s_loads hit ---
    {
        float dummy = 0.f;
        for (int i = tid; i < Tv * Cv; i += 512) dummy += xb[i];
        asm volatile("" :: "v"(dummy));
    }

    if (tid < 3) { s_flags[tid][0] = 0u; s_flags[tid][1] = 0u; }

    // --- prefetch x row 0 into SGPRs (scalar pipe; all-output asm) ---
    f32x4 q0 = {0.f,0.f,0.f,0.f}, q1 = q0, q2 = q0, q3 = q0, q4 = q0,
          q5 = q0, q6 = q0, q7 = q0, q8 = q0, q9 = q0;
    {
        const float* xr = xb;
        asm volatile(
            "s_load_dwordx4 %0, %[a], 0x0\n\t"
            "s_load_dwordx4 %1, %[a], 0x10\n\t"
            "s_load_dwordx4 %2, %[a], 0x20\n\t"
            "s_load_dwordx4 %3, %[a], 0x30\n\t"
            "s_load_dwordx4 %4, %[a], 0x40\n\t"
            "s_load_dwordx4 %5, %[a], 0x50\n\t"
            "s_load_dwordx4 %6, %[a], 0x60\n\t"
            "s_load_dwordx4 %7, %[a], 0x70\n\t"
            "s_load_dwordx4 %8, %[a], 0x80\n\t"
            "s_load_dwordx4 %9, %[a], 0x90"
            : "+s"(q0), "+s"(q1), "+s"(q2), "+s"(q3), "+s"(q4),
              "+s"(q5), "+s"(q6), "+s"(q7), "+s"(q8), "+s"(q9),
              [a] "+s"(xr)
            :);
    }

    __syncthreads();

    int rs = 2, wsl = 0, zsl = 1;   // read / write / zero slots (rotate)
    for (int t = 0; t < Tv + 2; ++t) {
        // ---- prev-step spike flags: one broadcast ds_read_b64 ----
        const u64 fl  = *(const u64*)(&s_flags[rs][0]);
        const u32 any1 = (u32)fl;
        const u32 any2 = (u32)(fl >> 32);

        // ================= L1 update for step t =================
        if (t < Tv) {
            // wait for the prefetched x row (tied operands = ordering fence)
            asm volatile("s_waitcnt lgkmcnt(0)"
                : "+s"(q0), "+s"(q1), "+s"(q2), "+s"(q3), "+s"(q4),
                  "+s"(q5), "+s"(q6), "+s"(q7), "+s"(q8), "+s"(q9));

            float c0 = 0.f, c1 = 0.f, c2 = 0.f, c3 = 0.f;
#define DOT_Q(Q, W) \
            c0 += (Q).x * (W).x; c1 += (Q).y * (W).y; \
            c2 += (Q).z * (W).z; c3 += (Q).w * (W).w;
            DOT_Q(q0, w1r[0]) DOT_Q(q1, w1r[1]) DOT_Q(q2, w1r[2])
            DOT_Q(q3, w1r[3]) DOT_Q(q4, w1r[4]) DOT_Q(q5, w1r[5])
            DOT_Q(q6, w1r[6]) DOT_Q(q7, w1r[7]) DOT_Q(q8, w1r[8])
            DOT_Q(q9, w1r[9])
#undef DOT_Q
            float acc = (c0 + c1) + (c2 + c3);

            // prefetch next row (redefines the q SGPRs; data flow orders
            // this after the consumption above; address is an output ->
            // distinct registers, no overlap hazard)
            if (t + 1 < Tv) {
                const float* xr = xb + (t + 1) * Cv;
                asm volatile(
                    "s_load_dwordx4 %0, %[a], 0x0\n\t"
                    "s_load_dwordx4 %1, %[a], 0x10\n\t"
                    "s_load_dwordx4 %2, %[a], 0x20\n\t"
                    "s_load_dwordx4 %3, %[a], 0x30\n\t"
                    "s_load_dwordx4 %4, %[a], 0x40\n\t"
                    "s_load_dwordx4 %5, %[a], 0x50\n\t"
                    "s_load_dwordx4 %6, %[a], 0x60\n\t"
                    "s_load_dwordx4 %7, %[a], 0x70\n\t"
                    "s_load_dwordx4 %8, %[a], 0x80\n\t"
                    "s_load_dwordx4 %9, %[a], 0x90"
                    : "+s"(q0), "+s"(q1), "+s"(q2), "+s"(q3), "+s"(q4),
                      "+s"(q5), "+s"(q6), "+s"(q7), "+s"(q8), "+s"(q9),
                      [a] "+s"(xr)
                    :);
            }

            if (any1) {   // recurrent gather — cold path, never on this data
                #pragma unroll
                for (int w = 0; w < 8; ++w) {
                    u64 m = s_m1[rs][w];
                    while (m) {
                        const int j = (w << 6) + __builtin_ctzll(m);
                        m &= (m - 1);
                        acc += Wrec[tid * H1v + j];
                    }
                }
            }
            v1 = al1 * (v1 - spk1 * THv) + (1.f - al1) * (acc - a1);
            const bool sp = (v1 >= THv);
            spk1 = sp ? 1.f : 0.f;
            a1 = rh1 * a1 + bb1 * spk1;
            const u64 bal = __ballot(sp);
            if (lane == 0) {
                s_m1[wsl][wv] = bal;
                if (bal) s_flags[wsl][0] = 1u;
            }
        }

        // ================= L2 update for step t-1 =================
        if ((tid < H2v) & (t >= 1) & (t <= Tv)) {
            float acc2 = 0.f;
            if (any1) {   // cold path
                #pragma unroll
                for (int w = 0; w < 8; ++w) {
                    u64 m = s_m1[rs][w];
                    while (m) {
                        const int j = (w << 6) + __builtin_ctzll(m);
                        m &= (m - 1);
                        acc2 += W2[tid * H1v + j];
                    }
                }
            }
            v2 = al2 * v2 + (1.f - al2) * (acc2 - a2);
            const bool sp2 = (v2 >= THv);
            a2 = rh2 * a2 + bb2 * (sp2 ? 1.f : 0.f);
            const u64 bal2 = __ballot(sp2);
            if (lane == 0) {
                s_m2[wsl][wv] = bal2;
                if (bal2) s_flags[wsl][1] = 1u;
            }
        }

        // ================= Out update for step t-2 =================
        if ((tid < Ov) & (t >= 2)) {
            float io = 0.f;
            if (any2) {   // cold path
                #pragma unroll
                for (int w = 0; w < 4; ++w) {
                    u64 m = s_m2[rs][w];
                    while (m) {
                        const int j = (w << 6) + __builtin_ctzll(m);
                        m &= (m - 1);
                        io += Wout[tid * H2v + j];
                    }
                }
            }
            vout = beta * vout + (1.f - beta) * io;
            osum += vout;
        }

        // zero the slot that becomes the write slot next iteration
        if (tid == 257) *(u64*)(&s_flags[zsl][0]) = 0ull;

        __syncthreads();
        const int tmp = rs; rs = wsl; wsl = zsl; zsl = tmp;
    }

    if (tid < Ov) out[b * Ov + tid] = osum / (float)Tv;
}

extern "C" void kernel_launch(void* const* d_in, const int* in_sizes, int n_in,
                              void* d_out, int out_size, void* d_ws, size_t ws_size,
                              hipStream_t stream)
{
    const float* x       = (const float*)d_in[0];
    const float* W1      = (const float*)d_in[1];
    const float* Wrec    = (const float*)d_in[2];
    const float* W2      = (const float*)d_in[3];
    const float* Wout    = (const float*)d_in[4];
    const float* alpha1  = (const float*)d_in[5];
    const float* rho1    = (const float*)d_in[6];
    const float* ba1     = (const float*)d_in[7];
    const float* alpha2  = (const float*)d_in[8];
    const float* rho2    = (const float*)d_in[9];
    const float* ba2     = (const float*)d_in[10];
    const float* beta_o  = (const float*)d_in[11];
    float* out = (float*)d_out;

    snn_main<<<dim3(Bv), dim3(512), 0, stream>>>(
        x, W1, Wrec, W2, Wout,
        alpha1, rho1, ba1, alpha2, rho2, ba2, beta_o, out);
}